// Round 4
// baseline (613.718 us; speedup 1.0000x reference)
//
#include <hip/hip_runtime.h>

#define F    64       // feature dim
#define EPW  160      // edges per wave (7813 waves total)
#define NG   3        // ceil(EPW/64) index-preload groups

// Detect whether idx arrays are int64 or int32 (wave-parallel, ~2us).
// Read as u64: if data is really int32, the high 32 bits of each "u64" is
// the next random index (>=1 w.p. 1-1/50000 each) -> some value >= 2^32.
// True int64 data (< 50000) never exceeds 2^32.
__global__ void detect_idx64(const unsigned long long* __restrict__ p,
                             int n_edges, int* __restrict__ flag) {
    const int t = threadIdx.x;                     // 64 threads
    int n = n_edges / 2; if (n > 256) n = 256;     // safe for both dtypes
    bool big = false;
    for (int k = 0; k < 4; ++k) {
        int id = t * 4 + k;
        if (id < n) big |= (p[id] >= (1ull << 32));
    }
    unsigned long long mask = __ballot(big);
    if (t == 0) *flag = (mask == 0ull) ? 1 : 0;
}

// Wave layout: sub = lane>>4 picks one of 4 edges per step, fq = (lane&15)*4
// picks a feature quad. One dwordx4 per lane => 1KB/wave/instr for Wij,
// 4x256B row segments for the x gather. Each 16-lane group owns the edge
// subsequence {base + 4k + sub} (sorted since idx_i sorted) and flushes its
// accumulator on segment change only.
__global__ __launch_bounds__(256, 4) void cfconv_kernel(
    const float* __restrict__ x,
    const float* __restrict__ Wij,
    const void* __restrict__ idx_i_raw,
    const void* __restrict__ idx_j_raw,
    float* __restrict__ y,
    const int* __restrict__ flag,
    int n_edges)
{
    const int gwave = (int)((blockIdx.x * blockDim.x + threadIdx.x) >> 6);
    const int lane  = threadIdx.x & 63;
    const int sub   = lane >> 4;            // edge slot within a 4-edge step
    const int fq    = (lane & 15) << 2;     // feature offset 0,4,...,60
    const long long e0 = (long long)gwave * EPW;
    if (e0 >= n_edges) return;
    const int cnt = (int)((e0 + EPW <= n_edges) ? EPW : (n_edges - e0));

    // ---- preload indices: lane L holds edge e0 + r*64 + L ----
    int iv[NG], jv[NG];
    if (*flag) {                            // int64 indices
        const long long* ii = (const long long*)idx_i_raw;
        const long long* jj = (const long long*)idx_j_raw;
        #pragma unroll
        for (int r = 0; r < NG; ++r) {
            int p = r * 64 + lane;
            if (p < cnt) { iv[r] = (int)ii[e0 + p]; jv[r] = (int)jj[e0 + p]; }
            else         { iv[r] = -1;              jv[r] = 0; }
        }
    } else {                                // int32 indices
        const int* ii = (const int*)idx_i_raw;
        const int* jj = (const int*)idx_j_raw;
        #pragma unroll
        for (int r = 0; r < NG; ++r) {
            int p = r * 64 + lane;
            if (p < cnt) { iv[r] = ii[e0 + p]; jv[r] = jj[e0 + p]; }
            else         { iv[r] = -1;         jv[r] = 0; }
        }
    }

    float4 acc = make_float4(0.f, 0.f, 0.f, 0.f);
    int cur_i = __shfl(iv[0], 0);           // valid: e0 < n_edges

    #pragma unroll
    for (int r = 0; r < NG; ++r) {          // 64-edge groups (static reg idx)
        const int gbase = r * 64;
        if (gbase >= cnt) break;
        for (int c = 0; c < 4; ++c) {       // chunks of 4 steps (16 edges)
            const int base = gbase + c * 16;
            if (base >= cnt) break;

            float4 xb[4], wb[4]; int ib[4];
            #pragma unroll
            for (int k = 0; k < 4; ++k) {   // issue 8 dwordx4 loads up front
                const int p   = base + k * 4 + sub;   // this lane's edge
                const int src = p - gbase;            // 0..63 within group
                const int j   = __shfl(jv[r], src);
                ib[k]         = __shfl(iv[r], src);
                if (p < cnt) {
                    wb[k] = *(const float4*)&Wij[(e0 + p) * (long long)F + fq];
                    xb[k] = *(const float4*)&x[(long long)j * F + fq];
                } else {
                    wb[k] = make_float4(0.f, 0.f, 0.f, 0.f);
                    xb[k] = make_float4(0.f, 0.f, 0.f, 0.f);
                    ib[k] = -1;
                }
            }
            #pragma unroll
            for (int k = 0; k < 4; ++k) {   // accumulate + rare flush
                if (ib[k] >= 0 && ib[k] != cur_i) {
                    atomicAdd(&y[(long long)cur_i * F + fq + 0], acc.x);
                    atomicAdd(&y[(long long)cur_i * F + fq + 1], acc.y);
                    atomicAdd(&y[(long long)cur_i * F + fq + 2], acc.z);
                    atomicAdd(&y[(long long)cur_i * F + fq + 3], acc.w);
                    acc = make_float4(0.f, 0.f, 0.f, 0.f);
                    cur_i = ib[k];
                }
                acc.x = fmaf(xb[k].x, wb[k].x, acc.x);
                acc.y = fmaf(xb[k].y, wb[k].y, acc.y);
                acc.z = fmaf(xb[k].z, wb[k].z, acc.z);
                acc.w = fmaf(xb[k].w, wb[k].w, acc.w);
            }
        }
    }
    atomicAdd(&y[(long long)cur_i * F + fq + 0], acc.x);
    atomicAdd(&y[(long long)cur_i * F + fq + 1], acc.y);
    atomicAdd(&y[(long long)cur_i * F + fq + 2], acc.z);
    atomicAdd(&y[(long long)cur_i * F + fq + 3], acc.w);
}

extern "C" void kernel_launch(void* const* d_in, const int* in_sizes, int n_in,
                              void* d_out, int out_size, void* d_ws, size_t ws_size,
                              hipStream_t stream) {
    const float* x    = (const float*)d_in[0];
    const float* Wij  = (const float*)d_in[1];
    const void*  ii   = d_in[2];
    const void*  jj   = d_in[3];
    float*       y    = (float*)d_out;
    int*         flag = (int*)d_ws;
    const int n_edges = in_sizes[2];        // idx_i element count

    hipMemsetAsync(d_out, 0, (size_t)out_size * sizeof(float), stream);
    detect_idx64<<<1, 64, 0, stream>>>((const unsigned long long*)jj, n_edges, flag);

    const int n_waves  = (n_edges + EPW - 1) / EPW;
    const int n_blocks = (n_waves + 3) / 4; // 4 waves (256 threads) per block
    cfconv_kernel<<<n_blocks, 256, 0, stream>>>(x, Wij, ii, jj, y, flag, n_edges);
}

// Round 5
// 454.043 us; speedup vs baseline: 1.3517x; 1.3517x over previous
//
#include <hip/hip_runtime.h>

#define F 64          // feature dim (known from reference)

// Detect whether idx arrays are int64 or int32 (wave-parallel, ~2us).
// Read as u64: if data is really int32, the high 32 bits of each "u64" is
// the next random index (>=1 w.p. 1-1/50000 each) -> some value >= 2^32.
// True int64 data (values < 50000) never exceeds 2^32.
__global__ void detect_idx64(const unsigned long long* __restrict__ p,
                             int n_edges, int* __restrict__ flag) {
    const int t = threadIdx.x;                     // 64 threads
    int n = n_edges / 2; if (n > 256) n = 256;     // safe for both dtypes
    bool big = false;
    for (int k = 0; k < 4; ++k) {
        int id = t * 4 + k;
        if (id < n) big |= (p[id] >= (1ull << 32));
    }
    unsigned long long mask = __ballot(big);
    if (t == 0) *flag = (mask == 0ull) ? 1 : 0;
}

// starts[a] = first edge p with idx_i[p] >= a  (idx_i is sorted).
// One thread per atom (plus one for the n_edges sentinel).
__global__ __launch_bounds__(256) void seg_starts(
    const void* __restrict__ idx_i_raw, const int* __restrict__ flag,
    int n_edges, int n_atoms, int* __restrict__ starts)
{
    const int a = blockIdx.x * blockDim.x + threadIdx.x;
    if (a > n_atoms) return;
    int lo = 0, hi = n_edges;
    if (*flag) {
        const long long* ii = (const long long*)idx_i_raw;
        while (lo < hi) { int mid = (lo + hi) >> 1;
                          if (ii[mid] < (long long)a) lo = mid + 1; else hi = mid; }
    } else {
        const int* ii = (const int*)idx_i_raw;
        while (lo < hi) { int mid = (lo + hi) >> 1;
                          if (ii[mid] < a) lo = mid + 1; else hi = mid; }
    }
    starts[a] = lo;
}

// One wave per atom: exclusive ownership of edge range [s,e) -> NO atomics.
// Lane layout: sub = lane>>4 picks one of 4 edges per step, fq = (lane&15)*4
// picks a feature quad -> every global access is a float4 (16B/lane).
// Cross-sub reduction via shfl_xor, single float4 store per row.
__global__ __launch_bounds__(256) void cfconv_kernel(
    const float* __restrict__ x,
    const float* __restrict__ Wij,
    const void* __restrict__ idx_j_raw,
    const int* __restrict__ starts,
    float* __restrict__ y,
    const int* __restrict__ flag,
    int n_atoms)
{
    const int a    = (int)((blockIdx.x * blockDim.x + threadIdx.x) >> 6);
    const int lane = threadIdx.x & 63;
    if (a >= n_atoms) return;
    const int sub = lane >> 4;              // edge slot within a 4-edge step
    const int fq  = (lane & 15) << 2;       // feature offset 0,4,...,60

    const int s = starts[a];
    const int e = starts[a + 1];

    const bool is64 = (*flag != 0);
    const long long* jj64 = (const long long*)idx_j_raw;
    const int*       jj32 = (const int*)idx_j_raw;

    float4 acc = make_float4(0.f, 0.f, 0.f, 0.f);

    for (int p0 = s + sub; p0 < e; p0 += 16) { // 4 predicated steps per iter
        float4 xb[4], wb[4];
        #pragma unroll
        for (int k = 0; k < 4; ++k) {          // issue up to 8 dwordx4 loads
            const int p = p0 + k * 4;
            if (p < e) {
                const int j = is64 ? (int)jj64[p] : jj32[p];
                wb[k] = *(const float4*)&Wij[(long long)p * F + fq];
                xb[k] = *(const float4*)&x[(long long)j * F + fq];
            } else {
                wb[k] = make_float4(0.f, 0.f, 0.f, 0.f);
                xb[k] = make_float4(0.f, 0.f, 0.f, 0.f);
            }
        }
        #pragma unroll
        for (int k = 0; k < 4; ++k) {
            acc.x = fmaf(xb[k].x, wb[k].x, acc.x);
            acc.y = fmaf(xb[k].y, wb[k].y, acc.y);
            acc.z = fmaf(xb[k].z, wb[k].z, acc.z);
            acc.w = fmaf(xb[k].w, wb[k].w, acc.w);
        }
    }

    // reduce across the 4 subs (lanes differing in bits 4,5)
    #pragma unroll
    for (int off = 16; off < 64; off <<= 1) {
        acc.x += __shfl_xor(acc.x, off);
        acc.y += __shfl_xor(acc.y, off);
        acc.z += __shfl_xor(acc.z, off);
        acc.w += __shfl_xor(acc.w, off);
    }
    if (sub == 0)                              // exclusive owner: plain store
        *(float4*)&y[(long long)a * F + fq] = acc;
}

extern "C" void kernel_launch(void* const* d_in, const int* in_sizes, int n_in,
                              void* d_out, int out_size, void* d_ws, size_t ws_size,
                              hipStream_t stream) {
    const float* x    = (const float*)d_in[0];
    const float* Wij  = (const float*)d_in[1];
    const void*  ii   = d_in[2];
    const void*  jj   = d_in[3];
    float*       y    = (float*)d_out;
    const int n_edges = in_sizes[2];           // idx_i element count
    const int n_atoms = out_size / F;

    int* flag   = (int*)d_ws;                  // ws[0:4)   : dtype flag
    int* starts = (int*)d_ws + 16;             // ws[64:...): segment starts

    detect_idx64<<<1, 64, 0, stream>>>((const unsigned long long*)jj, n_edges, flag);
    seg_starts<<<(n_atoms + 1 + 255) / 256, 256, 0, stream>>>(ii, flag, n_edges,
                                                              n_atoms, starts);
    // one wave per atom, 4 waves per block; every output row stored exactly
    // once -> no output memset needed
    cfconv_kernel<<<(n_atoms + 3) / 4, 256, 0, stream>>>(x, Wij, jj, starts, y,
                                                         flag, n_atoms);
}

// Round 9
// 447.850 us; speedup vs baseline: 1.3704x; 1.0138x over previous
//
#include <hip/hip_runtime.h>

#define F 64          // feature dim (known from reference)

typedef float vf4 __attribute__((ext_vector_type(4)));

// Detect whether idx arrays are int64 or int32 (wave-parallel, ~2us).
// Read as u64: if data is really int32, the high 32 bits of each "u64" is
// the next random index (>=1 w.p. 1-1/50000 each) -> some value >= 2^32.
// True int64 data (values < 50000) never exceeds 2^32.
__global__ void detect_idx64(const unsigned long long* __restrict__ p,
                             int n_edges, int* __restrict__ flag) {
    const int t = threadIdx.x;                     // 64 threads
    int n = n_edges / 2; if (n > 256) n = 256;     // safe for both dtypes
    bool big = false;
    for (int k = 0; k < 4; ++k) {
        int id = t * 4 + k;
        if (id < n) big |= (p[id] >= (1ull << 32));
    }
    unsigned long long mask = __ballot(big);
    if (t == 0) *flag = (mask == 0ull) ? 1 : 0;
}

// starts[a] = first edge p with idx_i[p] >= a  (idx_i is sorted).
__global__ __launch_bounds__(256) void seg_starts(
    const void* __restrict__ idx_i_raw, const int* __restrict__ flag,
    int n_edges, int n_atoms, int* __restrict__ starts)
{
    const int a = blockIdx.x * blockDim.x + threadIdx.x;
    if (a > n_atoms) return;
    int lo = 0, hi = n_edges;
    if (*flag) {
        const long long* ii = (const long long*)idx_i_raw;
        while (lo < hi) { int mid = (lo + hi) >> 1;
                          if (ii[mid] < (long long)a) lo = mid + 1; else hi = mid; }
    } else {
        const int* ii = (const int*)idx_i_raw;
        while (lo < hi) { int mid = (lo + hi) >> 1;
                          if (ii[mid] < a) lo = mid + 1; else hi = mid; }
    }
    starts[a] = lo;
}

// One wave per atom, exclusive edge range [s,e) -> no atomics, one store/row.
// Lane layout: sub = lane>>4 (edge slot), fq = (lane&15)*4 (feature quad);
// every access is a dwordx4. Per 64-edge group: one lane-parallel index load,
// then two 8-step bursts issuing 16 dwordx4 (16KB/wave) before consuming --
// deep in-flight queue to cover ~900cy HBM latency (R5 was burst-starved).
__global__ __launch_bounds__(256, 4) void cfconv_kernel(
    const float* __restrict__ x,
    const float* __restrict__ Wij,
    const void* __restrict__ idx_j_raw,
    const int* __restrict__ starts,
    float* __restrict__ y,
    const int* __restrict__ flag,
    int n_atoms)
{
    const int a    = (int)((blockIdx.x * blockDim.x + threadIdx.x) >> 6);
    const int lane = threadIdx.x & 63;
    if (a >= n_atoms) return;
    const int sub = lane >> 4;
    const int fq  = (lane & 15) << 2;

    const int s = starts[a];
    const int e = starts[a + 1];

    const bool is64 = (*flag != 0);
    const long long* jj64 = (const long long*)idx_j_raw;
    const int*       jj32 = (const int*)idx_j_raw;

    vf4 acc = (vf4)0.0f;

    for (int base = s; base < e; base += 64) {     // usually a single group
        // index preload: lane L holds idx_j[base+L]
        int jv = 0;
        if (base + lane < e)
            jv = is64 ? (int)jj64[base + lane] : jj32[base + lane];

        #pragma unroll
        for (int h = 0; h < 2; ++h) {              // two 32-edge bursts
            const int hb = h * 32;
            if (base + hb >= e) break;             // wave-uniform

            vf4 wb[8], xb[8];
            #pragma unroll
            for (int st = 0; st < 8; ++st) {       // issue 16 dwordx4 loads
                const int slot = hb + st * 4 + sub;
                const int p    = base + slot;
                const int j    = __shfl(jv, slot);
                if (p < e) {
                    wb[st] = __builtin_nontemporal_load(
                                 (const vf4*)&Wij[(long long)p * F + fq]);
                    xb[st] = *(const vf4*)&x[(long long)j * F + fq];
                } else {
                    wb[st] = (vf4)0.0f;
                    xb[st] = (vf4)0.0f;
                }
            }
            #pragma unroll
            for (int st = 0; st < 8; ++st)         // then consume
                acc += xb[st] * wb[st];
        }
    }

    // reduce across the 4 subs (lane bits 4,5)
    #pragma unroll
    for (int off = 16; off < 64; off <<= 1) {
        acc.x += __shfl_xor(acc.x, off);
        acc.y += __shfl_xor(acc.y, off);
        acc.z += __shfl_xor(acc.z, off);
        acc.w += __shfl_xor(acc.w, off);
    }
    if (sub == 0)                                  // exclusive owner: plain store
        *(vf4*)&y[(long long)a * F + fq] = acc;
}

extern "C" void kernel_launch(void* const* d_in, const int* in_sizes, int n_in,
                              void* d_out, int out_size, void* d_ws, size_t ws_size,
                              hipStream_t stream) {
    const float* x    = (const float*)d_in[0];
    const float* Wij  = (const float*)d_in[1];
    const void*  ii   = d_in[2];
    const void*  jj   = d_in[3];
    float*       y    = (float*)d_out;
    const int n_edges = in_sizes[2];               // idx_i element count
    const int n_atoms = out_size / F;

    int* flag   = (int*)d_ws;                      // ws[0:4)
    int* starts = (int*)d_ws + 16;                 // ws[64:...)

    detect_idx64<<<1, 64, 0, stream>>>((const unsigned long long*)jj, n_edges, flag);
    seg_starts<<<(n_atoms + 1 + 255) / 256, 256, 0, stream>>>(ii, flag, n_edges,
                                                              n_atoms, starts);
    cfconv_kernel<<<(n_atoms + 3) / 4, 256, 0, stream>>>(x, Wij, jj, starts, y,
                                                         flag, n_atoms);
}